// Round 8
// baseline (1552.584 us; speedup 1.0000x reference)
//
#include <hip/hip_runtime.h>
#include <cstdint>
#include <cstddef>

#define GN   16384
#define GIN  128
#define GOUT 64
#define LOG2E 1.44269504088896340736f

typedef __attribute__((ext_vector_type(8))) short short8;
typedef __attribute__((ext_vector_type(4))) float f32x4;
typedef __attribute__((ext_vector_type(4))) int   int4v;

__device__ __forceinline__ unsigned short f2bf(float f) {
  unsigned u = __float_as_uint(f);
  return (unsigned short)((u + 0x8000u) >> 16);   // round-half-up (cheap)
}

__device__ __forceinline__ unsigned short f2bf_rne(float f) {
  unsigned u = __float_as_uint(f);
  u += 0x7FFFu + ((u >> 16) & 1u);
  return (unsigned short)(u >> 16);
}

// ---------------------------------------------------------------------------
// prep (verified): Wh = x@W, f_src/f_dst (x log2e), Wh packed in MFMA
// B-fragment order: wpk[col_tile(512)][frag(4)][lane(64)][t(8)] bf16,
// col = col_tile*32 + (lane>>4)*8 + t, out-dim d = frag*16 + (lane&15).
// ---------------------------------------------------------------------------
__global__ __launch_bounds__(256) void prep_kernel(
    const float* __restrict__ x, const float* __restrict__ w,
    const float* __restrict__ aw, unsigned short* __restrict__ wpk,
    float* __restrict__ fs2, float* __restrict__ fd2)
{
  __shared__ float ws[GIN * GOUT];          // 32 KB
  __shared__ float red[2][64][4];

  const int t = threadIdx.x;
  const int rb = blockIdx.x * 64;

  for (int i = t; i < (GIN * GOUT) / 4; i += 256)
    ((float4*)ws)[i] = ((const float4*)w)[i];
  __syncthreads();

  const int r = t & 63, s = t >> 6;
  const int row = rb + r;
  const float* xr = x + (size_t)row * GIN;

  float acc[16];
#pragma unroll
  for (int d = 0; d < 16; ++d) acc[d] = 0.f;

  for (int kk = 0; kk < GIN; kk += 4) {
    float4 xv = *(const float4*)(xr + kk);
    float xa[4] = {xv.x, xv.y, xv.z, xv.w};
#pragma unroll
    for (int u = 0; u < 4; ++u) {
#pragma unroll
      for (int d = 0; d < 16; ++d)
        acc[d] += xa[u] * ws[(kk + u) * GOUT + s * 16 + d];
    }
  }

  const int jc = row >> 5;
  const int qq = (row & 31) >> 3;
  const int tt = row & 7;
  float psrc = 0.f, pdst = 0.f;
#pragma unroll
  for (int d = 0; d < 16; ++d) {
    const int dg = s * 16 + d;
    psrc += acc[d] * aw[dg];
    pdst += acc[d] * aw[GOUT + dg];
    const int f = dg >> 4, n = dg & 15;
    wpk[(size_t)jc * 4096 + f * 1024 + (qq * 16 + n) * 8 + tt] = f2bf_rne(acc[d]);
  }
  red[0][r][s] = psrc;
  red[1][r][s] = pdst;
  __syncthreads();
  if (s == 0) {
    float a_ = red[0][r][0] + red[0][r][1] + red[0][r][2] + red[0][r][3];
    float b_ = red[1][r][0] + red[1][r][1] + red[1][r][2] + red[1][r][3];
    fs2[row] = a_ * LOG2E;
    fd2[row] = b_ * LOG2E;
  }
}

// ---------------------------------------------------------------------------
// main v8: ONE wave owns 16 rows x ALL 16384 columns (no chunk dimension).
//  - adj streams: 16384 long sequential row-reads (vs 131072 128B-granule
//    interleaved streams in v7) -> DRAM page locality restored.
//  - single writer per row: den finishes in-registers, softmax division +
//    ELU fused here; no atomics, no partial slabs, no fin kernel, no memset.
// 1024 waves (256 blocks) = 4 waves/CU = 1/SIMD; unroll-2 covers latency.
// ---------------------------------------------------------------------------
__global__ __launch_bounds__(256) void gat_main(
    const int* __restrict__ adj, const unsigned short* __restrict__ wpk,
    const float* __restrict__ fs2, const float* __restrict__ fd2,
    float* __restrict__ out)
{
  const int wave  = blockIdx.x * 4 + (threadIdx.x >> 6);   // 0..1023
  const int lane  = threadIdx.x & 63;
  const int m = lane & 15;
  const int q = lane >> 4;
  const int row = wave * 16 + m;

  const float fs = fs2[row];

  const int4v*  __restrict__ arow = (const int4v*)(adj + (size_t)row * GN);
  const float4* __restrict__ fdv  = (const float4*)fd2;
  const short8* __restrict__ wpk8 = (const short8*)wpk;

  f32x4 acc0 = {0,0,0,0}, acc1 = {0,0,0,0}, acc2 = {0,0,0,0}, acc3 = {0,0,0,0};
  f32x4 accd = {0,0,0,0};

  short8 b_ones;
#pragma unroll
  for (int i = 0; i < 8; ++i) b_ones[i] = (short)0x3F80;  // bf16 1.0

  auto pcalc = [&](int a, float fd) -> unsigned short {
    float sv = fs + fd;
    float lv = fmaxf(sv, 0.02f * sv);       // lrelu (commutes with *log2e)
    float pe = __builtin_amdgcn_exp2f(lv);
    pe = (a != 0) ? pe : 0.f;
    return f2bf(pe);
  };

#pragma unroll 2
  for (int j = 0; j < GN; j += 32) {
    const int i4 = (j >> 2) + (q << 1);
    int4v a0 = __builtin_nontemporal_load(arow + i4);      // cols t=0..3
    int4v a1 = __builtin_nontemporal_load(arow + i4 + 1);  // cols t=4..7
    float4 f0 = fdv[i4];
    float4 f1 = fdv[i4 + 1];

    // packed B fragments: 4 contiguous 1 KB wave-loads
    const short8* wb = wpk8 + (size_t)(j >> 5) * 512 + lane;
    short8 b0 = wb[0];
    short8 b1 = wb[128];
    short8 b2 = wb[256];
    short8 b3 = wb[384];

    short8 af;
    af[0] = (short)pcalc(a0.x, f0.x);
    af[1] = (short)pcalc(a0.y, f0.y);
    af[2] = (short)pcalc(a0.z, f0.z);
    af[3] = (short)pcalc(a0.w, f0.w);
    af[4] = (short)pcalc(a1.x, f1.x);
    af[5] = (short)pcalc(a1.y, f1.y);
    af[6] = (short)pcalc(a1.z, f1.z);
    af[7] = (short)pcalc(a1.w, f1.w);

    acc0 = __builtin_amdgcn_mfma_f32_16x16x32_bf16(af, b0, acc0, 0, 0, 0);
    acc1 = __builtin_amdgcn_mfma_f32_16x16x32_bf16(af, b1, acc1, 0, 0, 0);
    acc2 = __builtin_amdgcn_mfma_f32_16x16x32_bf16(af, b2, acc2, 0, 0, 0);
    acc3 = __builtin_amdgcn_mfma_f32_16x16x32_bf16(af, b3, acc3, 0, 0, 0);
    accd = __builtin_amdgcn_mfma_f32_16x16x32_bf16(af, b_ones, accd, 0, 0, 0);
  }

  // fused epilogue: C/D layout D[row=q*4+r][col=m]; accd[r] = den of that
  // row (col-independent for B=ones). out = elu(num/den), single writer.
  const int orow0 = wave * 16 + q * 4;
#pragma unroll
  for (int r = 0; r < 4; ++r) {
    const float dv = accd[r];
    float* orow = out + (size_t)(orow0 + r) * GOUT + m;
    float v0 = acc0[r] / dv;
    float v1 = acc1[r] / dv;
    float v2 = acc2[r] / dv;
    float v3 = acc3[r] / dv;
    orow[0]  = (v0 > 0.f) ? v0 : expm1f(v0);
    orow[16] = (v1 > 0.f) ? v1 : expm1f(v1);
    orow[32] = (v2 > 0.f) ? v2 : expm1f(v2);
    orow[48] = (v3 > 0.f) ? v3 : expm1f(v3);
  }
}

extern "C" void kernel_launch(void* const* d_in, const int* in_sizes, int n_in,
                              void* d_out, int out_size, void* d_ws, size_t ws_size,
                              hipStream_t stream) {
  const float* x   = (const float*)d_in[0];
  const int*   adj = (const int*)d_in[1];
  const float* w   = (const float*)d_in[2];
  const float* aw  = (const float*)d_in[3];
  float* out = (float*)d_out;

  // ws layout (floats): fs2[N] | fd2[N] | wpk(bf16 64*N)
  float* fs2 = (float*)d_ws;
  float* fd2 = fs2 + GN;
  unsigned short* wpk = (unsigned short*)(fd2 + GN);
  // ~2.2 MB; everything fully written before read -> no memset needed

  prep_kernel<<<GN / 64, 256, 0, stream>>>(x, w, aw, wpk, fs2, fd2);
  gat_main<<<256, 256, 0, stream>>>(adj, wpk, fs2, fd2, out);
}

// Round 9
// 1391.465 us; speedup vs baseline: 1.1158x; 1.1158x over previous
//
#include <hip/hip_runtime.h>
#include <cstdint>
#include <cstddef>

#define GN   16384
#define GIN  128
#define GOUT 64
#define NCH  2           // column chunks (writers per row)
#define CT   128         // adj columns staged per tile
#define LROW 128         // LDS words per row (no pad; 2x read conflict is noise)
#define TILES ((GN / NCH) / CT)
#define LOG2E 1.44269504088896340736f

typedef __attribute__((ext_vector_type(8))) short short8;
typedef __attribute__((ext_vector_type(4))) float f32x4;
typedef __attribute__((ext_vector_type(4))) int   int4v;
typedef __attribute__((ext_vector_type(2))) int   int2v;

__device__ __forceinline__ unsigned short f2bf(float f) {
  unsigned u = __float_as_uint(f);
  return (unsigned short)((u + 0x8000u) >> 16);   // round-half-up (cheap)
}

__device__ __forceinline__ unsigned short f2bf_rne(float f) {
  unsigned u = __float_as_uint(f);
  u += 0x7FFFu + ((u >> 16) & 1u);
  return (unsigned short)(u >> 16);
}

// ---------------------------------------------------------------------------
// prep (verified): Wh = x@W, f_src/f_dst (x log2e), Wh packed in MFMA
// B-fragment order (1 KB contiguous per 16-dim fragment per 32 cols).
// ---------------------------------------------------------------------------
__global__ __launch_bounds__(256) void prep_kernel(
    const float* __restrict__ x, const float* __restrict__ w,
    const float* __restrict__ aw, unsigned short* __restrict__ wpk,
    float* __restrict__ fs2, float* __restrict__ fd2)
{
  __shared__ float ws[GIN * GOUT];          // 32 KB
  __shared__ float red[2][64][4];

  const int t = threadIdx.x;
  const int rb = blockIdx.x * 64;

  for (int i = t; i < (GIN * GOUT) / 4; i += 256)
    ((float4*)ws)[i] = ((const float4*)w)[i];
  __syncthreads();

  const int r = t & 63, s = t >> 6;
  const int row = rb + r;
  const float* xr = x + (size_t)row * GIN;

  float acc[16];
#pragma unroll
  for (int d = 0; d < 16; ++d) acc[d] = 0.f;

  for (int kk = 0; kk < GIN; kk += 4) {
    float4 xv = *(const float4*)(xr + kk);
    float xa[4] = {xv.x, xv.y, xv.z, xv.w};
#pragma unroll
    for (int u = 0; u < 4; ++u) {
#pragma unroll
      for (int d = 0; d < 16; ++d)
        acc[d] += xa[u] * ws[(kk + u) * GOUT + s * 16 + d];
    }
  }

  const int jc = row >> 5;
  const int qq = (row & 31) >> 3;
  const int tt = row & 7;
  float psrc = 0.f, pdst = 0.f;
#pragma unroll
  for (int d = 0; d < 16; ++d) {
    const int dg = s * 16 + d;
    psrc += acc[d] * aw[dg];
    pdst += acc[d] * aw[GOUT + dg];
    const int f = dg >> 4, n = dg & 15;
    wpk[(size_t)jc * 4096 + f * 1024 + (qq * 16 + n) * 8 + tt] = f2bf_rne(acc[d]);
  }
  red[0][r][s] = psrc;
  red[1][r][s] = pdst;
  __syncthreads();
  if (s == 0) {
    float a_ = red[0][r][0] + red[0][r][1] + red[0][r][2] + red[0][r][3];
    float b_ = red[1][r][0] + red[1][r][1] + red[1][r][2] + red[1][r][3];
    fs2[row] = a_ * LOG2E;
    fd2[row] = b_ * LOG2E;
  }
}

// ---------------------------------------------------------------------------
// main v9: adj staged through per-wave LDS tiles so every adj request is
// 512 B CONTIGUOUS from one row (one row per wave-instruction), fixing the
// 16-row/128B-scatter pattern shared by v1-v8. Double-buffered, barrier-free
// (each wave owns its 16 rows + private LDS slice). Per tile: wpk/fd loads
// are issued BEFORE the 16 adj prefetch loads so compute's vmcnt waits never
// drain the adj queue; adj regs -> LDS at the tail.
// 2048 waves (1024 blocks x 2 waves, 32 KB LDS) = 8 waves/CU.
// ---------------------------------------------------------------------------
__global__ __launch_bounds__(128) void gat_main(
    const int* __restrict__ adj, const unsigned short* __restrict__ wpk,
    const float* __restrict__ fs2, const float* __restrict__ fd2,
    float* __restrict__ nump, float* __restrict__ denp)
{
  __shared__ int lbuf[2 * 2 * 16 * LROW];   // 2 waves x 2 bufs x 16 rows x 512B

  const int widx = threadIdx.x >> 6;
  const int lane = threadIdx.x & 63;
  const int chunk = blockIdx.x >> 9;                  // 512 blocks per chunk
  const int strip = (blockIdx.x & 511) * 2 + widx;    // 0..1023
  const int m = lane & 15;
  const int q = lane >> 4;
  const int j0 = chunk * (GN / NCH);

  const float fs = fs2[strip * 16 + m];
  const int*    __restrict__ abase = adj + (size_t)(strip * 16) * GN + lane * 2;
  const float4* __restrict__ fdv   = (const float4*)fd2;
  const short8* __restrict__ wpk8  = (const short8*)wpk;
  int* lw = lbuf + widx * (2 * 16 * LROW);

  f32x4 acc0 = {0,0,0,0}, acc1 = {0,0,0,0}, acc2 = {0,0,0,0}, acc3 = {0,0,0,0};
  f32x4 accd = {0,0,0,0};

  short8 b_ones;
#pragma unroll
  for (int i = 0; i < 8; ++i) b_ones[i] = (short)0x3F80;  // bf16 1.0

  auto pcalc = [&](int a, float fd) -> unsigned short {
    float sv = fs + fd;
    float lv = fmaxf(sv, 0.02f * sv);       // lrelu (commutes with *log2e)
    float pe = __builtin_amdgcn_exp2f(lv);
    pe = (a != 0) ? pe : 0.f;
    return f2bf(pe);
  };

  int2v stage[16];
  auto load_tile = [&](int jt) {            // 16 x 512B-contiguous row reads
#pragma unroll
    for (int r = 0; r < 16; ++r)
      stage[r] = __builtin_nontemporal_load((const int2v*)(abase + (size_t)r * GN + jt));
  };
  auto write_tile = [&](int b) {            // 16 x ds_write_b64 (vmcnt waits here)
    int* ld = lw + b * (16 * LROW) + lane * 2;
#pragma unroll
    for (int r = 0; r < 16; ++r)
      *(int2v*)(ld + r * LROW) = stage[r];
  };

  load_tile(j0);
  write_tile(0);

  for (int t = 0; t < TILES; ++t) {
    const int jt = j0 + t * CT;
    const int buf = t & 1;

    // ---- consume-phase global loads FIRST (older in vmcnt order) ----
    short8 bw[4][4];
    float4 ff[4][2];
#pragma unroll
    for (int jj = 0; jj < 4; ++jj) {
      const int j = jt + jj * 32;
      const short8* wb = wpk8 + (size_t)(j >> 5) * 512 + lane;
      bw[jj][0] = wb[0];
      bw[jj][1] = wb[128];
      bw[jj][2] = wb[256];
      bw[jj][3] = wb[384];
      const int i4 = (j >> 2) + (q << 1);
      ff[jj][0] = fdv[i4];
      ff[jj][1] = fdv[i4 + 1];
    }

    // ---- adj prefetch for next tile (younger; never drained by compute) ----
    if (t + 1 < TILES) load_tile(jt + CT);

    // ---- compute from LDS + regs ----
    const int* lsrc = lw + buf * (16 * LROW) + m * LROW + q * 8;
#pragma unroll
    for (int jj = 0; jj < 4; ++jj) {
      int4v a0 = *(const int4v*)(lsrc + jj * 32);
      int4v a1 = *(const int4v*)(lsrc + jj * 32 + 4);
      float4 f0 = ff[jj][0], f1 = ff[jj][1];
      short8 af;
      af[0] = (short)pcalc(a0.x, f0.x);
      af[1] = (short)pcalc(a0.y, f0.y);
      af[2] = (short)pcalc(a0.z, f0.z);
      af[3] = (short)pcalc(a0.w, f0.w);
      af[4] = (short)pcalc(a1.x, f1.x);
      af[5] = (short)pcalc(a1.y, f1.y);
      af[6] = (short)pcalc(a1.z, f1.z);
      af[7] = (short)pcalc(a1.w, f1.w);
      acc0 = __builtin_amdgcn_mfma_f32_16x16x32_bf16(af, bw[jj][0], acc0, 0, 0, 0);
      acc1 = __builtin_amdgcn_mfma_f32_16x16x32_bf16(af, bw[jj][1], acc1, 0, 0, 0);
      acc2 = __builtin_amdgcn_mfma_f32_16x16x32_bf16(af, bw[jj][2], acc2, 0, 0, 0);
      acc3 = __builtin_amdgcn_mfma_f32_16x16x32_bf16(af, bw[jj][3], acc3, 0, 0, 0);
      accd = __builtin_amdgcn_mfma_f32_16x16x32_bf16(af, b_ones, accd, 0, 0, 0);
    }

    // ---- stage next tile into the other LDS buffer ----
    if (t + 1 < TILES) write_tile(buf ^ 1);
  }

  // epilogue: single writer per (chunk,row) -> plain stores to slab
  float* np = nump + (size_t)chunk * GN * GOUT;
  float* dp = denp + (size_t)chunk * GN;
  const int orow0 = strip * 16 + q * 4;
#pragma unroll
  for (int r = 0; r < 4; ++r) {
    float* nr = np + (size_t)(orow0 + r) * GOUT + m;
    __builtin_nontemporal_store(acc0[r], nr + 0);
    __builtin_nontemporal_store(acc1[r], nr + 16);
    __builtin_nontemporal_store(acc2[r], nr + 32);
    __builtin_nontemporal_store(acc3[r], nr + 48);
    if (m == 0) dp[orow0 + r] = accd[r];    // col-independent for B=ones
  }
}

// ---------------------------------------------------------------------------
// finalize: out = elu( (n0+n1) / (d0+d1) )
// ---------------------------------------------------------------------------
__global__ __launch_bounds__(256) void fin_kernel(
    const float* __restrict__ nump, const float* __restrict__ denp,
    float* __restrict__ out)
{
  const int g = blockIdx.x * 256 + threadIdx.x;
  if (g >= GN * GOUT) return;
  const int row = g >> 6;
  float s = nump[g] + nump[(size_t)GN * GOUT + g];
  float d = denp[row] + denp[GN + row];
  float v = s / d;
  out[g] = (v > 0.f) ? v : expm1f(v);
}

extern "C" void kernel_launch(void* const* d_in, const int* in_sizes, int n_in,
                              void* d_out, int out_size, void* d_ws, size_t ws_size,
                              hipStream_t stream) {
  const float* x   = (const float*)d_in[0];
  const int*   adj = (const int*)d_in[1];
  const float* w   = (const float*)d_in[2];
  const float* aw  = (const float*)d_in[3];
  float* out = (float*)d_out;

  // ws layout (floats): nump[2*N*64] | denp[2*N] | fs2[N] | fd2[N] | wpk(4MB span)
  float* nump = (float*)d_ws;
  float* denp = nump + (size_t)NCH * GN * GOUT;
  float* fs2  = denp + (size_t)NCH * GN;
  float* fd2  = fs2 + GN;
  unsigned short* wpk = (unsigned short*)(fd2 + GN);
  // everything fully written before read -> no memset needed

  prep_kernel<<<GN / 64, 256, 0, stream>>>(x, w, aw, wpk, fs2, fd2);
  gat_main<<<1024, 128, 0, stream>>>(adj, wpk, fs2, fd2, nump, denp);
  fin_kernel<<<(GN * GOUT) / 256, 256, 0, stream>>>(nump, denp, out);
}